// Round 10
// baseline (269.929 us; speedup 1.0000x reference)
//
#include <hip/hip_runtime.h>
#include <cstdint>
#include <cstddef>

#define N_NODES 30000
#define E_EDGES 480000
#define ETOT    510000   // E + N self-loops
#define IN_DIM  128
#define HID     256
#define HEADS   4
#define NEG_SLOPE 0.2f
#define DEG_BLOCKS 1993  // cdiv(ETOT,256)
#define NBSTRIDE 1088    // LDS bytes per 16-ch block: 32 rows*32B + 64B pad

static inline int cdiv(int a, int b){ return (a + b - 1) / b; }

typedef short bf16x8 __attribute__((ext_vector_type(8)));
typedef short bf16x4 __attribute__((ext_vector_type(4)));
typedef float f32x4  __attribute__((ext_vector_type(4)));

__device__ __forceinline__ unsigned short f2bf(float f) {
  unsigned u = __float_as_uint(f);
  unsigned r = (u + 0x7FFFu + ((u >> 16) & 1u)) >> 16;   // RNE
  return (unsigned short)r;
}
__device__ __forceinline__ float bf2f(unsigned short s) {
  return __uint_as_float((unsigned)s << 16);
}

// ---- setup: deg_count (blocks 0..1992) + x->bf16 + W transposes ----
__global__ __launch_bounds__(256) void setup(
    const int* __restrict__ ei, int* __restrict__ deg,
    const float* __restrict__ x, const float* __restrict__ W1,
    const float* __restrict__ Wp, const float* __restrict__ W2,
    ushort* __restrict__ xbf, ushort* __restrict__ w1t,
    ushort* __restrict__ wpt, ushort* __restrict__ w2t)
{
  int b = blockIdx.x;
  int t = threadIdx.x;
  if (b < DEG_BLOCKS) {
    int e = b * 256 + t;
    if (e < ETOT) {
      int d = (e < E_EDGES) ? ei[E_EDGES + e] : (e - E_EDGES);
      atomicAdd(&deg[d], 1);
    }
    return;
  }
  b -= DEG_BLOCKS;
  if (b < 3750) {                       // 3750*256*4 = N*IN
    int i = b * 256 + t;
    float4 v = ((const float4*)x)[i];
    ushort4 o;
    o.x = f2bf(v.x); o.y = f2bf(v.y); o.z = f2bf(v.z); o.w = f2bf(v.w);
    ((ushort4*)xbf)[i] = o;
  } else if (b < 3750 + 128) {
    int k = b - 3750;
    w1t[(size_t)t * IN_DIM + k] = f2bf(W1[(size_t)k * HID + t]);
  } else if (b < 3750 + 256) {
    int k = b - 3878;
    wpt[(size_t)t * IN_DIM + k] = f2bf(Wp[(size_t)k * HID + t]);
  } else {
    int k = b - 4006;
    w2t[(size_t)t * HID + k] = f2bf(W2[(size_t)k * HID + t]);
  }
}

// ---- bf16 MFMA GEMM + fused attn-logit epilogue (+ fused proj for layer 1) ----
template<int K, bool L1>
__global__ __launch_bounds__(256) void gemm_fused(
    const ushort* __restrict__ A,    // [n][K] bf16
    const ushort* __restrict__ WT,   // [NOUT][K] bf16 (W1t | Wpt contiguous for L1)
    const float* __restrict__ att_src, const float* __restrict__ att_dst,
    ushort* __restrict__ hout, float* __restrict__ esrc, float* __restrict__ edst,
    ushort* __restrict__ rout, const float* __restrict__ pbias, int n)
{
  const int wave = threadIdx.x >> 6;
  const int lane = threadIdx.x & 63;
  const int wr = wave >> 1, wc = wave & 1;
  const int brow = blockIdx.x * 128 + wr * 64;
  const int bcol = blockIdx.y * 128 + wc * 64;
  const int lrow = lane & 15;
  const int kgrp = lane >> 4;       // 0..3

  f32x4 acc[4][4] = {};
  for (int k0 = 0; k0 < K; k0 += 32) {
    const int kb = k0 + kgrp * 8;
    bf16x8 a[4], b[4];
    #pragma unroll
    for (int mi = 0; mi < 4; ++mi) {
      int r = brow + mi * 16 + lrow;
      r = min(r, n - 1);
      a[mi] = *(const bf16x8*)&A[(size_t)r * K + kb];
    }
    #pragma unroll
    for (int ni = 0; ni < 4; ++ni) {
      int c = bcol + ni * 16 + lrow;
      b[ni] = *(const bf16x8*)&WT[(size_t)c * K + kb];
    }
    #pragma unroll
    for (int mi = 0; mi < 4; ++mi)
      #pragma unroll
      for (int ni = 0; ni < 4; ++ni)
        acc[mi][ni] = __builtin_amdgcn_mfma_f32_16x16x32_bf16(a[mi], b[ni], acc[mi][ni], 0, 0, 0);
  }
  const bool proj = L1 && (bcol >= 256);
  // C write (C/D layout: col=lane&15, row=(lane>>4)*4+reg — m89-verified)
  #pragma unroll
  for (int mi = 0; mi < 4; ++mi) {
    #pragma unroll
    for (int r = 0; r < 4; ++r) {
      int row = brow + mi * 16 + kgrp * 4 + r;
      if (row < n) {
        #pragma unroll
        for (int ni = 0; ni < 4; ++ni) {
          int colg = bcol + ni * 16 + lrow;
          float v = acc[mi][ni][r];
          if (proj) {
            int c = colg - 256;
            rout[(size_t)row * HID + c] = f2bf(v + pbias[c]);
          } else {
            hout[(size_t)row * HID + colg] = f2bf(v);
          }
        }
      }
    }
  }
  // fused attention-logit epilogue: wave's 64 cols == head (bcol>>6)
  if (!proj) {
    const int hh = bcol >> 6;
    float as[4], ad[4];
    #pragma unroll
    for (int ni = 0; ni < 4; ++ni) {
      as[ni] = att_src[hh * 64 + ni * 16 + lrow];
      ad[ni] = att_dst[hh * 64 + ni * 16 + lrow];
    }
    #pragma unroll
    for (int mi = 0; mi < 4; ++mi) {
      #pragma unroll
      for (int r = 0; r < 4; ++r) {
        float vs = 0.f, vd = 0.f;
        #pragma unroll
        for (int ni = 0; ni < 4; ++ni) {
          float c = acc[mi][ni][r];
          vs += c * as[ni];
          vd += c * ad[ni];
        }
        #pragma unroll
        for (int m = 1; m <= 8; m <<= 1) {
          vs += __shfl_xor(vs, m);
          vd += __shfl_xor(vd, m);
        }
        int row = brow + mi * 16 + kgrp * 4 + r;
        if (lrow == 0 && row < n) {
          esrc[row * HEADS + hh] = vs;
          edst[row * HEADS + hh] = vd;
        }
      }
    }
  }
}

// ================= CSR build =================
__global__ __launch_bounds__(1024) void scan_rowptr(const int* __restrict__ deg,
                                                    int* __restrict__ rowptr,
                                                    int* __restrict__ cursor)
{
  const int CE = 30;
  __shared__ int sc[1024];
  int t = threadIdx.x;
  int base = t * CE;
  int local[CE];
  int s = 0;
  #pragma unroll
  for (int i = 0; i < CE; ++i) {
    int idx = base + i;
    int v = (idx < N_NODES) ? deg[idx] : 0;
    local[i] = s;
    s += v;
  }
  sc[t] = s;
  __syncthreads();
  for (int o = 1; o < 1024; o <<= 1) {
    int v = (t >= o) ? sc[t - o] : 0;
    __syncthreads();
    sc[t] += v;
    __syncthreads();
  }
  int off = sc[t] - s;
  #pragma unroll
  for (int i = 0; i < CE; ++i) {
    int idx = base + i;
    if (idx < N_NODES) {
      rowptr[idx] = off + local[i];
      cursor[idx] = off + local[i];
    }
  }
  if (t == 1023) rowptr[N_NODES] = off + s;
}

__global__ __launch_bounds__(256) void scatter_edges(const int* __restrict__ ei,
                                                     int* __restrict__ cursor,
                                                     int* __restrict__ col,
                                                     int* __restrict__ dstc)
{
  int e = blockIdx.x * blockDim.x + threadIdx.x;
  if (e >= ETOT) return;
  int s, d;
  if (e < E_EDGES) { s = ei[e]; d = ei[E_EDGES + e]; }
  else             { s = d = e - E_EDGES; }
  int pos = atomicAdd(&cursor[d], 1);
  col[pos] = s;
  dstc[pos] = d;
}

// ========== MFMA SpMM aggregation: one BLOCK per 16 dst nodes ==========
// Per 32-edge chunk: stage 32 h-rows -> LDS [16 nblk][32 k][16 ch];
// A = P (16 dst x 32 edges) assembled from per-edge (p,dst) LDS table;
// B via ds_read_b64_tr_b16 (lane vaddr = base+256*g+8*n -> col n, rows 8g..8g+3);
// wave w = head w = channels 64w..64w+63 (4 MFMA tiles).
template<bool WRITE_BF16>
__global__ __launch_bounds__(256) void gat_agg_mfma(
    const int* __restrict__ rowptr, const int* __restrict__ col,
    const int* __restrict__ dstc, const float* __restrict__ esrc,
    const float* __restrict__ edst, const ushort* __restrict__ h,
    const float* __restrict__ bias, const ushort* __restrict__ resid,
    const float* __restrict__ gamma, const float* __restrict__ beta,
    float* __restrict__ out_f32, ushort* __restrict__ out_bf16)
{
  __shared__ char lds_raw[16 * NBSTRIDE + 512 + 512];   // B-stage | pb | stats
  unsigned* pb   = (unsigned*)(lds_raw + 16 * NBSTRIDE);       // [32 k][4 heads]
  float*    stat = (float*)   (lds_raw + 16 * NBSTRIDE + 512); // [4 w][16 d][2]

  const int t    = threadIdx.x;
  const int wv   = t >> 6;
  const int lane = t & 63;
  const int g    = lane >> 4;          // k-group 0..3
  const int nn   = lane & 15;          // fragment col / A row
  const int d0   = blockIdx.x * 16;
  const int r0   = rowptr[d0];
  const int rend = rowptr[d0 + 16];
  const int nchunk = (rend - r0 + 31) >> 5;

  // staging geometry: thread -> row kk = t>>3, 8-lane covers 128B of the row/pass
  const int kk    = t >> 3;
  const int l8    = t & 7;
  const int snblk = l8 >> 1;           // +4 per pass
  const int swi   = (l8 & 1) * 16;     // byte offset within 32B row segment

  const unsigned Bb = (unsigned)(uintptr_t)lds_raw;
  const unsigned trbase = Bb + (unsigned)(g * 256 + nn * 8);

  f32x4 acc[4] = {};
  float dsum = 0.f;

  for (int c = 0; c < nchunk; ++c) {
    const int base = r0 + c * 32;
    // ---- stage 32 rows x 256 ch (bf16) into LDS ----
    int ec = min(base + kk, rend - 1);
    int srow = col[ec];
    const ushort* gp = &h[srow * HID + l8 * 8];
    #pragma unroll
    for (int i = 0; i < 4; ++i) {
      bf16x8 vrow = *(const bf16x8*)(gp + i * 64);
      *(bf16x8*)(lds_raw + (snblk + i * 4) * NBSTRIDE + kk * 32 + swi) = vrow;
    }
    // ---- per-edge p (4 heads) + dst tag ----
    if (t < 32) {
      int e = base + t;
      bool valid = e < rend;
      int ecl = min(e, rend - 1);
      int s = col[ecl];
      int dd = valid ? (dstc[e] - d0) : 255;
      float4 es = ((const float4*)esrc)[s];
      float4 ed = ((const float4*)edst)[d0 + (valid ? dd : 0)];
      uint4 w4;
      float v0 = es.x + ed.x; v0 = (v0 >= 0.f) ? v0 : NEG_SLOPE * v0;
      float v1 = es.y + ed.y; v1 = (v1 >= 0.f) ? v1 : NEG_SLOPE * v1;
      float v2 = es.z + ed.z; v2 = (v2 >= 0.f) ? v2 : NEG_SLOPE * v2;
      float v3 = es.w + ed.w; v3 = (v3 >= 0.f) ? v3 : NEG_SLOPE * v3;
      unsigned dhi = (unsigned)dd << 16;
      w4.x = valid ? ((unsigned)f2bf(__expf(v0)) | dhi) : 0xFF0000u;
      w4.y = valid ? ((unsigned)f2bf(__expf(v1)) | dhi) : 0xFF0000u;
      w4.z = valid ? ((unsigned)f2bf(__expf(v2)) | dhi) : 0xFF0000u;
      w4.w = valid ? ((unsigned)f2bf(__expf(v3)) | dhi) : 0xFF0000u;
      ((uint4*)pb)[t] = w4;
    }
    __syncthreads();

    // ---- B fragments: 2 tr-reads per channel tile ----
    bf16x4 tr[4][2];
    #pragma unroll
    for (int nb = 0; nb < 4; ++nb) {
      unsigned a32 = trbase + (unsigned)((wv * 4 + nb) * NBSTRIDE);
      asm volatile("ds_read_b64_tr_b16 %0, %2 offset:0\n\t"
                   "ds_read_b64_tr_b16 %1, %2 offset:128"
                   : "=v"(tr[nb][0]), "=v"(tr[nb][1]) : "v"(a32));
    }
    // ---- A fragment: row = nn, k = 8g+j ----
    bf16x8 afrag;
    #pragma unroll
    for (int j = 0; j < 8; ++j) {
      unsigned word = pb[(8 * g + j) * 4 + wv];
      unsigned short pv = ((word >> 16) == (unsigned)nn) ? (unsigned short)word : 0;
      afrag[j] = (short)pv;
      dsum += bf2f(pv);
    }
    asm volatile("s_waitcnt lgkmcnt(0)" ::: "memory");
    __builtin_amdgcn_sched_barrier(0);
    #pragma unroll
    for (int nb = 0; nb < 4; ++nb) {
      bf16x8 bfrag = __builtin_shufflevector(tr[nb][0], tr[nb][1], 0,1,2,3,4,5,6,7);
      acc[nb] = __builtin_amdgcn_mfma_f32_16x16x32_bf16(afrag, bfrag, acc[nb], 0, 0, 0);
    }
    __syncthreads();   // before next chunk overwrites LDS
  }

  // ---- denominator: reduce over k-groups; lane (l&15)=d holds denom[d][head=wv]
  dsum += __shfl_xor(dsum, 16);
  dsum += __shfl_xor(dsum, 32);

  float rdn[4];
  #pragma unroll
  for (int r = 0; r < 4; ++r)
    rdn[r] = 1.f / __shfl(dsum, 4 * g + r);   // denom for dst row 4g+r

  // ---- finalize: v = acc/den + bias + resid; LN partials per wave ----
  float bia[4], gam[4], bet[4];
  #pragma unroll
  for (int nb = 0; nb < 4; ++nb) {
    int ch = wv * 64 + nb * 16 + nn;
    bia[nb] = bias[ch]; gam[nb] = gamma[ch]; bet[nb] = beta[ch];
  }
  float v[4][4];     // [nb][r]
  float s1[4] = {}, s2[4] = {};
  #pragma unroll
  for (int r = 0; r < 4; ++r) {
    int drow = d0 + 4 * g + r;
    #pragma unroll
    for (int nb = 0; nb < 4; ++nb) {
      int ch = wv * 64 + nb * 16 + nn;
      float x = acc[nb][r] * rdn[r] + bia[nb] + bf2f(resid[drow * HID + ch]);
      v[nb][r] = x;
      s1[r] += x; s2[r] += x * x;
    }
  }
  #pragma unroll
  for (int r = 0; r < 4; ++r) {
    #pragma unroll
    for (int m = 1; m <= 8; m <<= 1) {
      s1[r] += __shfl_xor(s1[r], m);
      s2[r] += __shfl_xor(s2[r], m);
    }
  }
  if (nn == 0) {
    #pragma unroll
    for (int r = 0; r < 4; ++r) {
      stat[(wv * 16 + 4 * g + r) * 2 + 0] = s1[r];
      stat[(wv * 16 + 4 * g + r) * 2 + 1] = s2[r];
    }
  }
  __syncthreads();
  #pragma unroll
  for (int r = 0; r < 4; ++r) {
    int dl = 4 * g + r;
    float S1 = stat[(0 * 16 + dl) * 2] + stat[(1 * 16 + dl) * 2]
             + stat[(2 * 16 + dl) * 2] + stat[(3 * 16 + dl) * 2];
    float S2 = stat[(0 * 16 + dl) * 2 + 1] + stat[(1 * 16 + dl) * 2 + 1]
             + stat[(2 * 16 + dl) * 2 + 1] + stat[(3 * 16 + dl) * 2 + 1];
    float mu = S1 * (1.f / HID);
    float var = S2 * (1.f / HID) - mu * mu;
    float rr = rsqrtf(var + 1e-5f);
    int drow = d0 + dl;
    #pragma unroll
    for (int nb = 0; nb < 4; ++nb) {
      int ch = wv * 64 + nb * 16 + nn;
      float y = (v[nb][r] - mu) * rr * gam[nb] + bet[nb];
      y = (y > 0.f) ? y : expm1f(y);
      if (WRITE_BF16) out_bf16[drow * HID + ch] = f2bf(y);
      else            out_f32[drow * HID + ch] = y;
    }
  }
}

extern "C" void kernel_launch(void* const* d_in, const int* in_sizes, int n_in,
                              void* d_out, int out_size, void* d_ws, size_t ws_size,
                              hipStream_t stream) {
  const float* x   = (const float*)d_in[0];
  const int*   ei  = (const int*)d_in[1];
  const float* W1  = (const float*)d_in[2];
  const float* as1 = (const float*)d_in[3];
  const float* ad1 = (const float*)d_in[4];
  const float* b1  = (const float*)d_in[5];
  const float* W2  = (const float*)d_in[6];
  const float* as2 = (const float*)d_in[7];
  const float* ad2 = (const float*)d_in[8];
  const float* b2  = (const float*)d_in[9];
  const float* g1  = (const float*)d_in[10];
  const float* be1 = (const float*)d_in[11];
  const float* g2  = (const float*)d_in[12];
  const float* be2 = (const float*)d_in[13];
  const float* Wp  = (const float*)d_in[14];
  const float* bp  = (const float*)d_in[15];
  float* out = (float*)d_out;

  const size_t NB16 = (size_t)N_NODES * HID * sizeof(ushort);  // 15.36 MB
  const size_t XB16 = (size_t)N_NODES * IN_DIM * sizeof(ushort);
  const size_t NH_BUF = (size_t)N_NODES * HEADS * sizeof(float);
  char* ws = (char*)d_ws;
  size_t off = 0;
  ushort* hbf   = (ushort*)(ws + off); off += NB16;            // h (bf16 gather table)
  ushort* hAbf  = (ushort*)(ws + off); off += NB16;            // hA / layer-2 resid
  ushort* rbf   = (ushort*)(ws + off); off += NB16;            // layer-1 resid (bf16)
  ushort* xbf   = (ushort*)(ws + off); off += XB16;
  ushort* w1t   = (ushort*)(ws + off); off += (size_t)HID * IN_DIM * 2;  // [w1t|wpt]
  ushort* wpt   = (ushort*)(ws + off); off += (size_t)HID * IN_DIM * 2;
  ushort* w2t   = (ushort*)(ws + off); off += (size_t)HID * HID * 2;
  float*  esrc  = (float*) (ws + off); off += NH_BUF;
  float*  edstb = (float*) (ws + off); off += NH_BUF;
  int*    deg    = (int*)(ws + off); off += (size_t)N_NODES * 4;
  int*    rowptr = (int*)(ws + off); off += (size_t)(N_NODES + 1) * 4;
  int*    cursor = (int*)(ws + off); off += (size_t)N_NODES * 4;
  int*    col    = (int*)(ws + off); off += (size_t)ETOT * 4;
  int*    dstc   = (int*)(ws + off); off += (size_t)ETOT * 4;

  // ---- CSR build + precision prep (fused) ----
  hipMemsetAsync(deg, 0, (size_t)N_NODES * 4, stream);
  setup<<<DEG_BLOCKS + 3750 + 128 + 128 + 256, 256, 0, stream>>>(
      ei, deg, x, W1, Wp, W2, xbf, w1t, wpt, w2t);
  scan_rowptr<<<1, 1024, 0, stream>>>(deg, rowptr, cursor);
  scatter_edges<<<cdiv(ETOT, 256), 256, 0, stream>>>(ei, cursor, col, dstc);

  // ================= Layer 1 (W1 and Wp fused: 512 output cols) =================
  gemm_fused<IN_DIM, true><<<dim3(cdiv(N_NODES, 128), 4), 256, 0, stream>>>(
      xbf, w1t, as1, ad1, hbf, esrc, edstb, rbf, bp, N_NODES);
  gat_agg_mfma<true><<<N_NODES / 16, 256, 0, stream>>>(
      rowptr, col, dstc, esrc, edstb, hbf, b1, rbf, g1, be1, nullptr, hAbf);

  // ================= Layer 2 =================
  gemm_fused<HID, false><<<dim3(cdiv(N_NODES, 128), 2), 256, 0, stream>>>(
      hAbf, w2t, as2, ad2, hbf, esrc, edstb, nullptr, nullptr, N_NODES);
  gat_agg_mfma<false><<<N_NODES / 16, 256, 0, stream>>>(
      rowptr, col, dstc, esrc, edstb, hbf, b2, hAbf, g2, be2, out, nullptr);
}